// Round 4
// baseline (557.162 us; speedup 1.0000x reference)
//
#include <hip/hip_runtime.h>
#include <hip/hip_bf16.h>
#include <math.h>

#define DIM    1024
#define HEADS  16
#define HD     64
#define BSZ    4
#define SEQ    2048
#define NTOK   (BSZ*SEQ)          // 8192

typedef __attribute__((ext_vector_type(4))) float f32x4;
typedef __attribute__((ext_vector_type(8))) short bf16x8;

__device__ __forceinline__ unsigned short f2bf(float f){
  union { float f; unsigned int i; } v; v.f = f;
  unsigned int u = v.i;
  u += 0x7fffu + ((u >> 16) & 1u);   // RNE
  return (unsigned short)(u >> 16);
}
__device__ __forceinline__ void gld_lds16(const void* g, void* l){
  __builtin_amdgcn_global_load_lds(
      (const __attribute__((address_space(1))) unsigned int*)g,
      (__attribute__((address_space(3))) unsigned int*)l, 16, 0, 0);
}

// ---------------- prep: fp32 -> bf16 convert ----------------
__global__ __launch_bounds__(256) void cvt_bf16(const float* __restrict__ src,
                                                unsigned short* __restrict__ dst, int n4){
  int i = blockIdx.x*256 + threadIdx.x;
  if (i < n4){
    float4 v = ((const float4*)src)[i];
    ushort4 o;
    o.x = f2bf(v.x); o.y = f2bf(v.y); o.z = f2bf(v.z); o.w = f2bf(v.w);
    ((ushort4*)dst)[i] = o;
  }
}

// ---------------- prep: RoPE cos/sin table (SEQ x 32 fp32) ----------------
__global__ __launch_bounds__(256) void rope_tab(float* __restrict__ ctab,
                                                float* __restrict__ stab){
  int i = blockIdx.x*256 + threadIdx.x;     // exactly SEQ*32 threads
  int t = i >> 5, j = i & 31;
  float freq = (float)t * powf(10000.0f, -(float)j * (1.0f/32.0f));
  ctab[i] = cosf(freq);
  stab[i] = sinf(freq);
}

// ---------------- bt-GEMM: C = A(MxK) * B(NxK)^T, bf16 MFMA ----------------
// MODE 0: QKV projection + fused RoPE, outb = qkv (3,B,H,T,HD) bf16
// MODE 1: O projection + x residual, outf = h (NTOK x DIM) fp32  (d_out)
template<int MODE>
__global__ __launch_bounds__(256) void gemm_bt(
    const unsigned short* __restrict__ A,
    const unsigned short* __restrict__ Bw,
    const float* __restrict__ ctab, const float* __restrict__ stab,
    const float* __restrict__ xres,
    unsigned short* __restrict__ outb,
    float* __restrict__ outf,
    int M, int N, int K)
{
  __shared__ unsigned short As[128*64];
  __shared__ unsigned short Bs[128*64];
  const int tid = threadIdx.x;
  const int w = tid >> 6, l = tid & 63;
  const int lr = l & 15, lg = l >> 4;
  const int nbm = M >> 7;
  const int bm = blockIdx.x % nbm;
  const int bn = blockIdx.x / nbm;
  const int wr = w >> 1, wc = w & 1;          // 2x2 waves -> 64x64 each
  const int srow = l >> 3;                    // staging: row within 8-row chunk
  const int scol = (l & 7) * 8;               // staging: element offset in row

  const f32x4 fzero = {0.f,0.f,0.f,0.f};
  f32x4 acc[4][4];
#pragma unroll
  for (int mt = 0; mt < 4; ++mt)
#pragma unroll
    for (int nt = 0; nt < 4; ++nt) acc[mt][nt] = fzero;

  const size_t abase = (size_t)(bm*128)*K;
  const size_t bbase = (size_t)(bn*128)*K;

  for (int k0 = 0; k0 < K; k0 += 64) {
    __syncthreads();                           // prev-iter LDS reads done
#pragma unroll
    for (int ci = 0; ci < 4; ++ci) {
      int c = w*4 + ci;                        // wave-uniform chunk id
      int row = c*8 + srow;
      gld_lds16(A  + abase + (size_t)row*K + k0 + scol, (char*)As + c*1024);
      gld_lds16(Bw + bbase + (size_t)row*K + k0 + scol, (char*)Bs + c*1024);
    }
    __syncthreads();                           // staging drained before reads
#pragma unroll
    for (int ks = 0; ks < 2; ++ks) {
      bf16x8 af[4], bfr[4];
#pragma unroll
      for (int mt = 0; mt < 4; ++mt)
        af[mt] = *(const bf16x8*)(As + (wr*64 + mt*16 + lr)*64 + ks*32 + lg*8);
#pragma unroll
      for (int nt = 0; nt < 4; ++nt)
        bfr[nt] = *(const bf16x8*)(Bs + (wc*64 + nt*16 + lr)*64 + ks*32 + lg*8);
#pragma unroll
      for (int mt = 0; mt < 4; ++mt)
#pragma unroll
        for (int nt = 0; nt < 4; ++nt)
          acc[mt][nt] = __builtin_amdgcn_mfma_f32_16x16x32_bf16(af[mt], bfr[nt], acc[mt][nt], 0, 0, 0);
    }
  }

  const int mb = bm*128 + wr*64;
  const int nb = bn*128 + wc*64;               // 64-col block => single head/section
  if (MODE == 0) {
    const int which = nb >> 10;                // 0=q 1=k 2=v
    const int h = (nb & 1023) >> 6;
    const size_t secbase = (size_t)which * ((size_t)BSZ*HEADS*SEQ*HD);
#pragma unroll
    for (int mt = 0; mt < 4; ++mt) {
#pragma unroll
      for (int r = 0; r < 4; ++r) {
        int m = mb + mt*16 + lg*4 + r;         // C/D layout: row=(lane>>4)*4+r
        int b = m >> 11, t = m & (SEQ-1);
        float v[4];
#pragma unroll
        for (int nt = 0; nt < 4; ++nt) v[nt] = acc[mt][nt][r];
        if (which < 2) {                       // RoPE on q,k: pair (hd, hd+32) = (nt, nt+2)
#pragma unroll
          for (int nt = 0; nt < 2; ++nt) {
            int hd = nt*16 + lr;               // < 32
            float c = ctab[t*32 + hd], s = stab[t*32 + hd];
            float v0 = v[nt], v1 = v[nt+2];
            v[nt]   = v0*c - v1*s;
            v[nt+2] = v1*c + v0*s;
          }
        }
        size_t ob = secbase + ((size_t)(b*HEADS + h)*SEQ + t) * HD;
#pragma unroll
        for (int nt = 0; nt < 4; ++nt)
          outb[ob + nt*16 + lr] = f2bf(v[nt]);
      }
    }
  } else {
#pragma unroll
    for (int mt = 0; mt < 4; ++mt) {
#pragma unroll
      for (int r = 0; r < 4; ++r) {
        int m = mb + mt*16 + lg*4 + r;
        size_t rowb = (size_t)m * DIM;
#pragma unroll
        for (int nt = 0; nt < 4; ++nt) {
          int n = nb + nt*16 + lr;
          outf[rowb + n] = acc[mt][nt][r] + xres[rowb + n];
        }
      }
    }
  }
}

// ---------------- flash attention ----------------
// block = (b,h, 64 q-rows), 4 waves x 16 q-rows. LDS stride 88 => 2-way bank alias (free).
__global__ __launch_bounds__(256) void attn_fwd(
    const unsigned short* __restrict__ qkv,
    const int* __restrict__ amask,
    unsigned short* __restrict__ aout)
{
  __shared__ unsigned short Kt[64*88];   // [key][d]
  __shared__ unsigned short Vt[64*88];   // [d][key]  (transposed)
  __shared__ unsigned short Pt[64*88];   // [q][key]
  const int tid = threadIdx.x;
  const int w = tid >> 6, l = tid & 63;
  const int lr = l & 15, lg = l >> 4;
  const int bh = blockIdx.x >> 5;        // b*16+h
  const int qb = blockIdx.x & 31;
  const int b = bh >> 4;
  const size_t SEC = (size_t)BSZ*HEADS*SEQ*HD;
  const size_t qoff = (size_t)bh * SEQ * HD;
  const unsigned short* Qp = qkv + qoff;
  const unsigned short* Kp = qkv + SEC + qoff;
  const unsigned short* Vp = qkv + 2*SEC + qoff;

  // Q A-frags held in registers for the whole kernel
  const int qrow = qb*64 + w*16 + lr;
  bf16x8 qf[2];
#pragma unroll
  for (int ks = 0; ks < 2; ++ks)
    qf[ks] = *(const bf16x8*)(Qp + (size_t)qrow*HD + ks*32 + lg*8);

  const f32x4 fzero = {0.f,0.f,0.f,0.f};
  f32x4 o[4];
#pragma unroll
  for (int dt = 0; dt < 4; ++dt) o[dt] = fzero;
  float mrun[4], lrun[4];
#pragma unroll
  for (int r = 0; r < 4; ++r){ mrun[r] = -1e30f; lrun[r] = 0.f; }

  for (int kt = 0; kt < SEQ/64; ++kt) {
    __syncthreads();                      // prev-iter LDS reads done
    for (int c = tid; c < 512; c += 256) {
      int row = c >> 3, c8 = (c & 7) * 8;
      *(bf16x8*)(Kt + row*88 + c8) = *(const bf16x8*)(Kp + (size_t)(kt*64+row)*HD + c8);
      bf16x8 vv = *(const bf16x8*)(Vp + (size_t)(kt*64+row)*HD + c8);
#pragma unroll
      for (int j = 0; j < 8; ++j)
        Vt[(c8+j)*88 + row] = ((unsigned short*)&vv)[j];
    }
    __syncthreads();

    // S = Q K^T for this wave's 16 q-rows x 64 keys
    f32x4 s[4];
#pragma unroll
    for (int nt = 0; nt < 4; ++nt) s[nt] = fzero;
#pragma unroll
    for (int ks = 0; ks < 2; ++ks) {
#pragma unroll
      for (int nt = 0; nt < 4; ++nt) {
        bf16x8 kf = *(const bf16x8*)(Kt + (nt*16+lr)*88 + ks*32 + lg*8);
        s[nt] = __builtin_amdgcn_mfma_f32_16x16x32_bf16(qf[ks], kf, s[nt], 0, 0, 0);
      }
    }

    // online softmax (fp32); lane holds col=lr of tiles nt, rows lg*4+r
    float addm[4];
#pragma unroll
    for (int nt = 0; nt < 4; ++nt)
      addm[nt] = (1.0f - (float)amask[b*SEQ + kt*64 + nt*16 + lr]) * 1e9f;
    float corr[4];
    float pv[4][4];
#pragma unroll
    for (int r = 0; r < 4; ++r) {
      float mx = -1e30f;
#pragma unroll
      for (int nt = 0; nt < 4; ++nt) {
        float vv = s[nt][r] * 0.125f - addm[nt];
        pv[nt][r] = vv;
        mx = fmaxf(mx, vv);
      }
#pragma unroll
      for (int d = 8; d >= 1; d >>= 1) mx = fmaxf(mx, __shfl_xor(mx, d));
      float mnew = fmaxf(mrun[r], mx);
      corr[r] = __expf(mrun[r] - mnew);
      float rsum = 0.f;
#pragma unroll
      for (int nt = 0; nt < 4; ++nt) {
        float p = __expf(pv[nt][r] - mnew);
        pv[nt][r] = p;
        rsum += p;
      }
#pragma unroll
      for (int d = 8; d >= 1; d >>= 1) rsum += __shfl_xor(rsum, d);
      lrun[r] = lrun[r] * corr[r] + rsum;
      mrun[r] = mnew;
    }
#pragma unroll
    for (int dt = 0; dt < 4; ++dt)
#pragma unroll
      for (int r = 0; r < 4; ++r)
        o[dt][r] *= corr[r];

    // P -> LDS (C-layout scatter), re-read as A-frags
#pragma unroll
    for (int nt = 0; nt < 4; ++nt)
#pragma unroll
      for (int r = 0; r < 4; ++r)
        Pt[(w*16 + lg*4 + r)*88 + nt*16 + lr] = f2bf(pv[nt][r]);
    __syncthreads();

#pragma unroll
    for (int ks = 0; ks < 2; ++ks) {
      bf16x8 pf = *(const bf16x8*)(Pt + (w*16+lr)*88 + ks*32 + lg*8);
#pragma unroll
      for (int dt = 0; dt < 4; ++dt) {
        bf16x8 vf = *(const bf16x8*)(Vt + (dt*16+lr)*88 + ks*32 + lg*8);
        o[dt] = __builtin_amdgcn_mfma_f32_16x16x32_bf16(pf, vf, o[dt], 0, 0, 0);
      }
    }
  }

  const int h = bh & (HEADS-1);
#pragma unroll
  for (int r = 0; r < 4; ++r) {
    float inv = 1.0f / lrun[r];
    int t = qb*64 + w*16 + lg*4 + r;
    size_t rowb = (size_t)(b*SEQ + t) * DIM + h*HD;
#pragma unroll
    for (int dt = 0; dt < 4; ++dt)
      aout[rowb + dt*16 + lr] = f2bf(o[dt][r] * inv);
  }
}

// ---------------- LayerNorm: fp32 in-place on d_out ----------------
__global__ __launch_bounds__(256) void layernorm_inplace(
    float* __restrict__ hbuf,
    const float* __restrict__ gamma, const float* __restrict__ beta)
{
  const int row = blockIdx.x;
  const int tid = threadIdx.x;
  const int w = tid >> 6, l = tid & 63;
  __shared__ float red[8];
  float* hr = hbuf + (size_t)row * DIM;
  float4 v = *(const float4*)(hr + tid*4);
  float s = v.x+v.y+v.z+v.w;
#pragma unroll
  for (int d = 32; d >= 1; d >>= 1) s += __shfl_xor(s, d);
  if (l == 0) red[w] = s;
  __syncthreads();
  float mu = (red[0]+red[1]+red[2]+red[3]) * (1.0f/DIM);
  float d0=v.x-mu, d1=v.y-mu, d2=v.z-mu, d3=v.w-mu;
  float q = d0*d0+d1*d1+d2*d2+d3*d3;
#pragma unroll
  for (int d = 32; d >= 1; d >>= 1) q += __shfl_xor(q, d);
  if (l == 0) red[4+w] = q;
  __syncthreads();
  float var = (red[4]+red[5]+red[6]+red[7]) * (1.0f/DIM);
  float rstd = rsqrtf(var + 1e-5f);
  int c = tid*4;
  float4 ou;
  ou.x = d0*rstd*gamma[c+0]+beta[c+0];
  ou.y = d1*rstd*gamma[c+1]+beta[c+1];
  ou.z = d2*rstd*gamma[c+2]+beta[c+2];
  ou.w = d3*rstd*gamma[c+3]+beta[c+3];
  *(float4*)(hr + c) = ou;
}

extern "C" void kernel_launch(void* const* d_in, const int* in_sizes, int n_in,
                              void* d_out, int out_size, void* d_ws, size_t ws_size,
                              hipStream_t stream) {
  const float* x     = (const float*)d_in[0];
  const int*   amask = (const int*)  d_in[1];
  const float* Wq    = (const float*)d_in[2];
  const float* Wk    = (const float*)d_in[3];
  const float* Wv    = (const float*)d_in[4];
  const float* Wo    = (const float*)d_in[5];
  const float* gamma = (const float*)d_in[6];
  const float* beta  = (const float*)d_in[7];

  // workspace layout (~92.8 MB; round-1 evidence says ws_size >= this)
  unsigned short* xb   = (unsigned short*)d_ws;                       // NTOK*DIM bf16
  unsigned short* Wqkv = xb + (size_t)NTOK*DIM;                       // 3*DIM*DIM bf16
  unsigned short* Wob  = Wqkv + (size_t)3*DIM*DIM;                    // DIM*DIM bf16
  unsigned short* qkv  = Wob + (size_t)DIM*DIM;                       // 3*NTOK*DIM bf16
  unsigned short* aout = qkv + (size_t)3*NTOK*DIM;                    // NTOK*DIM bf16
  float* ctab = (float*)(aout + (size_t)NTOK*DIM);                    // SEQ*32 f32
  float* stab = ctab + SEQ*32;

  float* hout = (float*)d_out;   // fp32 h, then LN in-place

  // prep
  cvt_bf16<<<(NTOK*DIM/4 + 255)/256, 256, 0, stream>>>(x,  xb,               NTOK*DIM/4);
  cvt_bf16<<<(DIM*DIM/4  + 255)/256, 256, 0, stream>>>(Wq, Wqkv,             DIM*DIM/4);
  cvt_bf16<<<(DIM*DIM/4  + 255)/256, 256, 0, stream>>>(Wk, Wqkv + DIM*DIM,   DIM*DIM/4);
  cvt_bf16<<<(DIM*DIM/4  + 255)/256, 256, 0, stream>>>(Wv, Wqkv + 2*DIM*DIM, DIM*DIM/4);
  cvt_bf16<<<(DIM*DIM/4  + 255)/256, 256, 0, stream>>>(Wo, Wob,              DIM*DIM/4);
  rope_tab<<<SEQ*32/256, 256, 0, stream>>>(ctab, stab);

  // QKV projection + RoPE  (M=8192, N=3072, K=1024)
  gemm_bt<0><<<(NTOK/128)*(3*DIM/128), 256, 0, stream>>>(
      xb, Wqkv, ctab, stab, nullptr, qkv, nullptr, NTOK, 3*DIM, DIM);

  // attention
  attn_fwd<<<BSZ*HEADS*(SEQ/64), 256, 0, stream>>>(qkv, amask, aout);

  // O projection + residual  (M=8192, N=1024, K=1024) -> fp32 h in d_out
  gemm_bt<1><<<(NTOK/128)*(DIM/128), 256, 0, stream>>>(
      aout, Wob, nullptr, nullptr, x, nullptr, hout, NTOK, DIM, DIM);

  // LayerNorm in-place on d_out (fp32)
  layernorm_inplace<<<NTOK, 256, 0, stream>>>(hout, gamma, beta);
}

// Round 5
// 474.581 us; speedup vs baseline: 1.1740x; 1.1740x over previous
//
#include <hip/hip_runtime.h>
#include <hip/hip_bf16.h>
#include <math.h>

#define DIM    1024
#define HEADS  16
#define HD     64
#define BSZ    4
#define SEQ    2048
#define NTOK   (BSZ*SEQ)          // 8192

typedef __attribute__((ext_vector_type(4))) float f32x4;
typedef __attribute__((ext_vector_type(8))) short bf16x8;

__device__ __forceinline__ unsigned short f2bf(float f){
  union { float f; unsigned int i; } v; v.f = f;
  unsigned int u = v.i;
  u += 0x7fffu + ((u >> 16) & 1u);   // RNE
  return (unsigned short)(u >> 16);
}
__device__ __forceinline__ void gld_lds16(const void* g, void* l){
  __builtin_amdgcn_global_load_lds(
      (const __attribute__((address_space(1))) unsigned int*)g,
      (__attribute__((address_space(3))) unsigned int*)l, 16, 0, 0);
}

// ---------------- prep: fp32 -> bf16 convert ----------------
__global__ __launch_bounds__(256) void cvt_bf16(const float* __restrict__ src,
                                                unsigned short* __restrict__ dst, int n4){
  int i = blockIdx.x*256 + threadIdx.x;
  if (i < n4){
    float4 v = ((const float4*)src)[i];
    ushort4 o;
    o.x = f2bf(v.x); o.y = f2bf(v.y); o.z = f2bf(v.z); o.w = f2bf(v.w);
    ((ushort4*)dst)[i] = o;
  }
}

// ---------------- prep: RoPE cos/sin table (SEQ x 32 fp32) ----------------
__global__ __launch_bounds__(256) void rope_tab(float* __restrict__ ctab,
                                                float* __restrict__ stab){
  int i = blockIdx.x*256 + threadIdx.x;     // exactly SEQ*32 threads
  int t = i >> 5, j = i & 31;
  float freq = (float)t * powf(10000.0f, -(float)j * (1.0f/32.0f));
  ctab[i] = cosf(freq);
  stab[i] = sinf(freq);
}

// ---------------- bt-GEMM: C = A(MxK) * B(NxK)^T, bf16 MFMA ----------------
// MODE 0: QKV projection + fused RoPE (+0.125 scale on q), outb = qkv (3,B,H,T,HD) bf16
// MODE 1: O projection + x residual, outf = h (NTOK x DIM) fp32  (d_out)
template<int MODE>
__global__ __launch_bounds__(256) void gemm_bt(
    const unsigned short* __restrict__ A,
    const unsigned short* __restrict__ Bw,
    const float* __restrict__ ctab, const float* __restrict__ stab,
    const float* __restrict__ xres,
    unsigned short* __restrict__ outb,
    float* __restrict__ outf,
    int M, int N, int K)
{
  __shared__ unsigned short As[128*64];
  __shared__ unsigned short Bs[128*64];
  const int tid = threadIdx.x;
  const int w = tid >> 6, l = tid & 63;
  const int lr = l & 15, lg = l >> 4;
  const int nbm = M >> 7;
  const int bm = blockIdx.x % nbm;
  const int bn = blockIdx.x / nbm;
  const int wr = w >> 1, wc = w & 1;          // 2x2 waves -> 64x64 each
  const int srow = l >> 3;                    // staging: row within 8-row chunk
  const int scol = (l & 7) * 8;               // staging: element offset in row

  const f32x4 fzero = {0.f,0.f,0.f,0.f};
  f32x4 acc[4][4];
#pragma unroll
  for (int mt = 0; mt < 4; ++mt)
#pragma unroll
    for (int nt = 0; nt < 4; ++nt) acc[mt][nt] = fzero;

  const size_t abase = (size_t)(bm*128)*K;
  const size_t bbase = (size_t)(bn*128)*K;

  for (int k0 = 0; k0 < K; k0 += 64) {
    __syncthreads();                           // prev-iter LDS reads done
#pragma unroll
    for (int ci = 0; ci < 4; ++ci) {
      int c = w*4 + ci;                        // wave-uniform chunk id
      int row = c*8 + srow;
      gld_lds16(A  + abase + (size_t)row*K + k0 + scol, (char*)As + c*1024);
      gld_lds16(Bw + bbase + (size_t)row*K + k0 + scol, (char*)Bs + c*1024);
    }
    __syncthreads();                           // staging drained before reads
#pragma unroll
    for (int ks = 0; ks < 2; ++ks) {
      bf16x8 af[4], bfr[4];
#pragma unroll
      for (int mt = 0; mt < 4; ++mt)
        af[mt] = *(const bf16x8*)(As + (wr*64 + mt*16 + lr)*64 + ks*32 + lg*8);
#pragma unroll
      for (int nt = 0; nt < 4; ++nt)
        bfr[nt] = *(const bf16x8*)(Bs + (wc*64 + nt*16 + lr)*64 + ks*32 + lg*8);
#pragma unroll
      for (int mt = 0; mt < 4; ++mt)
#pragma unroll
        for (int nt = 0; nt < 4; ++nt)
          acc[mt][nt] = __builtin_amdgcn_mfma_f32_16x16x32_bf16(af[mt], bfr[nt], acc[mt][nt], 0, 0, 0);
    }
  }

  const int mb = bm*128 + wr*64;
  const int nb = bn*128 + wc*64;               // 64-col block => single head/section
  if (MODE == 0) {
    const int which = nb >> 10;                // 0=q 1=k 2=v
    const int h = (nb & 1023) >> 6;
    const size_t secbase = (size_t)which * ((size_t)BSZ*HEADS*SEQ*HD);
#pragma unroll
    for (int mt = 0; mt < 4; ++mt) {
#pragma unroll
      for (int r = 0; r < 4; ++r) {
        int m = mb + mt*16 + lg*4 + r;         // C/D layout: row=(lane>>4)*4+r
        int b = m >> 11, t = m & (SEQ-1);
        float v[4];
#pragma unroll
        for (int nt = 0; nt < 4; ++nt) v[nt] = acc[mt][nt][r];
        if (which < 2) {                       // RoPE on q,k: pair (hd, hd+32) = (nt, nt+2)
#pragma unroll
          for (int nt = 0; nt < 2; ++nt) {
            int hd = nt*16 + lr;               // < 32
            float c = ctab[t*32 + hd], s = stab[t*32 + hd];
            float v0 = v[nt], v1 = v[nt+2];
            v[nt]   = v0*c - v1*s;
            v[nt+2] = v1*c + v0*s;
          }
          if (which == 0) {                    // fold softmax scale 1/sqrt(64) into q
#pragma unroll
            for (int nt = 0; nt < 4; ++nt) v[nt] *= 0.125f;
          }
        }
        size_t ob = secbase + ((size_t)(b*HEADS + h)*SEQ + t) * HD;
#pragma unroll
        for (int nt = 0; nt < 4; ++nt)
          outb[ob + nt*16 + lr] = f2bf(v[nt]);
      }
    }
  } else {
#pragma unroll
    for (int mt = 0; mt < 4; ++mt) {
#pragma unroll
      for (int r = 0; r < 4; ++r) {
        int m = mb + mt*16 + lg*4 + r;
        size_t rowb = (size_t)m * DIM;
#pragma unroll
        for (int nt = 0; nt < 4; ++nt) {
          int n = nb + nt*16 + lr;
          outf[rowb + n] = acc[mt][nt][r] + xres[rowb + n];
        }
      }
    }
  }
}

// ---------------- V global transpose: [b][h][t][d] -> [b][h][d][t] ----------------
__global__ __launch_bounds__(256) void vtrans(
    const unsigned short* __restrict__ vin,
    unsigned short* __restrict__ vT)
{
  __shared__ unsigned short T[64][65];
  const int tid = threadIdx.x;
  const int bh = blockIdx.x >> 5;
  const int t0 = (blockIdx.x & 31) * 64;
  const unsigned short* src = vin + ((size_t)bh*SEQ + t0) * HD;
  for (int i = tid; i < 512; i += 256) {
    int r = i >> 3, c8 = (i & 7) * 8;
    *(bf16x8*)(&T[r][c8]) = *(const bf16x8*)(src + r*HD + c8);
  }
  __syncthreads();
  for (int i = tid; i < 512; i += 256) {
    int d = i >> 3, tc8 = (i & 7) * 8;
    bf16x8 o;
#pragma unroll
    for (int j = 0; j < 8; ++j) ((unsigned short*)&o)[j] = T[tc8+j][d];
    *(bf16x8*)(vT + ((size_t)bh*HD + d)*SEQ + t0 + tc8) = o;
  }
}

// ---------------- flash attention ----------------
// block = (b,h, 64 q-rows), 4 waves x 16 q-rows.
// K row-major, V pre-transposed [d][t]; LDS stride 72 (144B -> bank step 4, 2-way = free).
// Double-buffered staging: issue loads early, 1 barrier per K-tile.
#define LST 72
__global__ __launch_bounds__(256) void attn_fwd(
    const unsigned short* __restrict__ qkv,   // q,k sections [b][h][t][d]
    const unsigned short* __restrict__ vT,    // [b][h][d][t]
    const int* __restrict__ amask,
    unsigned short* __restrict__ aout)
{
  __shared__ unsigned short Kls[2][64*LST];
  __shared__ unsigned short Vls[2][64*LST];
  __shared__ unsigned short Pls[64*LST];
  const int tid = threadIdx.x;
  const int w = tid >> 6, l = tid & 63;
  const int lr = l & 15, lg = l >> 4;
  const int bh = blockIdx.x >> 5;        // b*16+h
  const int qb = blockIdx.x & 31;
  const int b = bh >> 4;
  const size_t SEC = (size_t)BSZ*HEADS*SEQ*HD;
  const unsigned short* Qp = qkv + (size_t)bh*SEQ*HD;
  const unsigned short* Kp = Qp + SEC;
  const unsigned short* Vp = vT + (size_t)bh*HD*SEQ;

  // staging decomposition: 4096 elems / 256 threads = 2 chunks of 8
  const int r0 = tid >> 3;               // 0..31
  const int c0 = (tid & 7) * 8;          // 0..56
  const int r1 = r0 + 32;

  // Q A-frags held in registers (prescaled by 0.125 in gemm0)
  const int qrow = qb*64 + w*16 + lr;
  bf16x8 qf[2];
#pragma unroll
  for (int ks = 0; ks < 2; ++ks)
    qf[ks] = *(const bf16x8*)(Qp + (size_t)qrow*HD + ks*32 + lg*8);

  const f32x4 fzero = {0.f,0.f,0.f,0.f};
  f32x4 o[4];
#pragma unroll
  for (int dt = 0; dt < 4; ++dt) o[dt] = fzero;
  float mrun[4], lrun[4];
#pragma unroll
  for (int r = 0; r < 4; ++r){ mrun[r] = -1e30f; lrun[r] = 0.f; }

  // prologue: stage tile 0 into buf 0
  {
    bf16x8 ka = *(const bf16x8*)(Kp + (size_t)r0*HD + c0);
    bf16x8 kb_= *(const bf16x8*)(Kp + (size_t)r1*HD + c0);
    bf16x8 va = *(const bf16x8*)(Vp + (size_t)r0*SEQ + c0);
    bf16x8 vb_= *(const bf16x8*)(Vp + (size_t)r1*SEQ + c0);
    *(bf16x8*)(&Kls[0][r0*LST + c0]) = ka;
    *(bf16x8*)(&Kls[0][r1*LST + c0]) = kb_;
    *(bf16x8*)(&Vls[0][r0*LST + c0]) = va;
    *(bf16x8*)(&Vls[0][r1*LST + c0]) = vb_;
  }
  __syncthreads();

  for (int kt = 0; kt < SEQ/64; ++kt) {
    const int cur = kt & 1;
    // issue next-tile loads early (latency hidden under compute)
    bf16x8 ka, kb_, va, vb_;
    const bool more = (kt+1 < SEQ/64);
    if (more) {
      const size_t kb0 = (size_t)((kt+1)*64);
      ka = *(const bf16x8*)(Kp + (kb0 + r0)*HD + c0);
      kb_= *(const bf16x8*)(Kp + (kb0 + r1)*HD + c0);
      va = *(const bf16x8*)(Vp + (size_t)r0*SEQ + kb0 + c0);
      vb_= *(const bf16x8*)(Vp + (size_t)r1*SEQ + kb0 + c0);
    }

    // S = Q K^T for this wave's 16 q-rows x 64 keys
    f32x4 s[4];
#pragma unroll
    for (int nt = 0; nt < 4; ++nt) s[nt] = fzero;
#pragma unroll
    for (int ks = 0; ks < 2; ++ks) {
#pragma unroll
      for (int nt = 0; nt < 4; ++nt) {
        bf16x8 kf = *(const bf16x8*)(&Kls[cur][(nt*16+lr)*LST + ks*32 + lg*8]);
        s[nt] = __builtin_amdgcn_mfma_f32_16x16x32_bf16(qf[ks], kf, s[nt], 0, 0, 0);
      }
    }

    // online softmax (fp32); lane holds col(key)=lr of tiles nt, rows(q) lg*4+r
    float addm[4];
#pragma unroll
    for (int nt = 0; nt < 4; ++nt)
      addm[nt] = (1.0f - (float)amask[b*SEQ + kt*64 + nt*16 + lr]) * 1e9f;
    float corr[4];
    float pv[4][4];
#pragma unroll
    for (int r = 0; r < 4; ++r) {
      float mx = -1e30f;
#pragma unroll
      for (int nt = 0; nt < 4; ++nt) {
        float vv = s[nt][r] - addm[nt];
        pv[nt][r] = vv;
        mx = fmaxf(mx, vv);
      }
#pragma unroll
      for (int d = 8; d >= 1; d >>= 1) mx = fmaxf(mx, __shfl_xor(mx, d));
      float mnew = fmaxf(mrun[r], mx);
      corr[r] = __expf(mrun[r] - mnew);
      float rsum = 0.f;
#pragma unroll
      for (int nt = 0; nt < 4; ++nt) {
        float p = __expf(pv[nt][r] - mnew);
        pv[nt][r] = p;
        rsum += p;
      }
#pragma unroll
      for (int d = 8; d >= 1; d >>= 1) rsum += __shfl_xor(rsum, d);
      lrun[r] = lrun[r] * corr[r] + rsum;
      mrun[r] = mnew;
    }
#pragma unroll
    for (int dt = 0; dt < 4; ++dt)
#pragma unroll
      for (int r = 0; r < 4; ++r)
        o[dt][r] *= corr[r];

    // P -> per-wave LDS region (no barrier needed), re-read as A-frags
#pragma unroll
    for (int nt = 0; nt < 4; ++nt)
#pragma unroll
      for (int r = 0; r < 4; ++r)
        Pls[(w*16 + lg*4 + r)*LST + nt*16 + lr] = f2bf(pv[nt][r]);

#pragma unroll
    for (int ks = 0; ks < 2; ++ks) {
      bf16x8 pf = *(const bf16x8*)(&Pls[(w*16+lr)*LST + ks*32 + lg*8]);
#pragma unroll
      for (int dt = 0; dt < 4; ++dt) {
        bf16x8 vf = *(const bf16x8*)(&Vls[cur][(dt*16+lr)*LST + ks*32 + lg*8]);
        o[dt] = __builtin_amdgcn_mfma_f32_16x16x32_bf16(pf, vf, o[dt], 0, 0, 0);
      }
    }

    if (more) {
      const int nxt = cur ^ 1;
      *(bf16x8*)(&Kls[nxt][r0*LST + c0]) = ka;
      *(bf16x8*)(&Kls[nxt][r1*LST + c0]) = kb_;
      *(bf16x8*)(&Vls[nxt][r0*LST + c0]) = va;
      *(bf16x8*)(&Vls[nxt][r1*LST + c0]) = vb_;
      __syncthreads();
    }
  }

  const int h = bh & (HEADS-1);
#pragma unroll
  for (int r = 0; r < 4; ++r) {
    float inv = 1.0f / lrun[r];
    int t = qb*64 + w*16 + lg*4 + r;
    size_t rowb = (size_t)(b*SEQ + t) * DIM + h*HD;
#pragma unroll
    for (int dt = 0; dt < 4; ++dt)
      aout[rowb + dt*16 + lr] = f2bf(o[dt][r] * inv);
  }
}

// ---------------- LayerNorm: fp32 in-place on d_out ----------------
__global__ __launch_bounds__(256) void layernorm_inplace(
    float* __restrict__ hbuf,
    const float* __restrict__ gamma, const float* __restrict__ beta)
{
  const int row = blockIdx.x;
  const int tid = threadIdx.x;
  const int w = tid >> 6, l = tid & 63;
  __shared__ float red[8];
  float* hr = hbuf + (size_t)row * DIM;
  float4 v = *(const float4*)(hr + tid*4);
  float s = v.x+v.y+v.z+v.w;
#pragma unroll
  for (int d = 32; d >= 1; d >>= 1) s += __shfl_xor(s, d);
  if (l == 0) red[w] = s;
  __syncthreads();
  float mu = (red[0]+red[1]+red[2]+red[3]) * (1.0f/DIM);
  float d0=v.x-mu, d1=v.y-mu, d2=v.z-mu, d3=v.w-mu;
  float q = d0*d0+d1*d1+d2*d2+d3*d3;
#pragma unroll
  for (int d = 32; d >= 1; d >>= 1) q += __shfl_xor(q, d);
  if (l == 0) red[4+w] = q;
  __syncthreads();
  float var = (red[4]+red[5]+red[6]+red[7]) * (1.0f/DIM);
  float rstd = rsqrtf(var + 1e-5f);
  int c = tid*4;
  float4 ou;
  ou.x = d0*rstd*gamma[c+0]+beta[c+0];
  ou.y = d1*rstd*gamma[c+1]+beta[c+1];
  ou.z = d2*rstd*gamma[c+2]+beta[c+2];
  ou.w = d3*rstd*gamma[c+3]+beta[c+3];
  *(float4*)(hr + c) = ou;
}

extern "C" void kernel_launch(void* const* d_in, const int* in_sizes, int n_in,
                              void* d_out, int out_size, void* d_ws, size_t ws_size,
                              hipStream_t stream) {
  const float* x     = (const float*)d_in[0];
  const int*   amask = (const int*)  d_in[1];
  const float* Wq    = (const float*)d_in[2];
  const float* Wk    = (const float*)d_in[3];
  const float* Wv    = (const float*)d_in[4];
  const float* Wo    = (const float*)d_in[5];
  const float* gamma = (const float*)d_in[6];
  const float* beta  = (const float*)d_in[7];

  // workspace layout (~92.8 MB, proven to fit)
  unsigned short* xb   = (unsigned short*)d_ws;                       // NTOK*DIM bf16 (dead after gemm0 -> reused as vT)
  unsigned short* Wqkv = xb + (size_t)NTOK*DIM;                       // 3*DIM*DIM bf16
  unsigned short* Wob  = Wqkv + (size_t)3*DIM*DIM;                    // DIM*DIM bf16
  unsigned short* qkv  = Wob + (size_t)DIM*DIM;                       // 3*NTOK*DIM bf16
  unsigned short* aout = qkv + (size_t)3*NTOK*DIM;                    // NTOK*DIM bf16
  float* ctab = (float*)(aout + (size_t)NTOK*DIM);                    // SEQ*32 f32
  float* stab = ctab + SEQ*32;

  unsigned short* vT = xb;       // V^T [b][h][d][t], reuses xb after gemm0
  float* hout = (float*)d_out;   // fp32 h, then LN in-place

  // prep
  cvt_bf16<<<(NTOK*DIM/4 + 255)/256, 256, 0, stream>>>(x,  xb,               NTOK*DIM/4);
  cvt_bf16<<<(DIM*DIM/4  + 255)/256, 256, 0, stream>>>(Wq, Wqkv,             DIM*DIM/4);
  cvt_bf16<<<(DIM*DIM/4  + 255)/256, 256, 0, stream>>>(Wk, Wqkv + DIM*DIM,   DIM*DIM/4);
  cvt_bf16<<<(DIM*DIM/4  + 255)/256, 256, 0, stream>>>(Wv, Wqkv + 2*DIM*DIM, DIM*DIM/4);
  cvt_bf16<<<(DIM*DIM/4  + 255)/256, 256, 0, stream>>>(Wo, Wob,              DIM*DIM/4);
  rope_tab<<<SEQ*32/256, 256, 0, stream>>>(ctab, stab);

  // QKV projection + RoPE + q-scale  (M=8192, N=3072, K=1024)
  gemm_bt<0><<<(NTOK/128)*(3*DIM/128), 256, 0, stream>>>(
      xb, Wqkv, ctab, stab, nullptr, qkv, nullptr, NTOK, 3*DIM, DIM);

  // V -> V^T (xb region is dead now)
  vtrans<<<BSZ*HEADS*(SEQ/64), 256, 0, stream>>>(qkv + (size_t)2*BSZ*HEADS*SEQ*HD, vT);

  // attention
  attn_fwd<<<BSZ*HEADS*(SEQ/64), 256, 0, stream>>>(qkv, vT, amask, aout);

  // O projection + residual  (M=8192, N=1024, K=1024) -> fp32 h in d_out
  gemm_bt<1><<<(NTOK/128)*(DIM/128), 256, 0, stream>>>(
      aout, Wob, nullptr, nullptr, x, nullptr, hout, NTOK, DIM, DIM);

  // LayerNorm in-place on d_out (fp32)
  layernorm_inplace<<<NTOK, 256, 0, stream>>>(hout, gamma, beta);
}

// Round 6
// 456.093 us; speedup vs baseline: 1.2216x; 1.0405x over previous
//
#include <hip/hip_runtime.h>
#include <hip/hip_bf16.h>
#include <math.h>

#define DIM    1024
#define HEADS  16
#define HD     64
#define BSZ    4
#define SEQ    2048
#define NTOK   (BSZ*SEQ)          // 8192

typedef __attribute__((ext_vector_type(4))) float f32x4;
typedef __attribute__((ext_vector_type(8))) short bf16x8;

__device__ __forceinline__ unsigned short f2bf(float f){
  union { float f; unsigned int i; } v; v.f = f;
  unsigned int u = v.i;
  u += 0x7fffu + ((u >> 16) & 1u);   // RNE
  return (unsigned short)(u >> 16);
}
__device__ __forceinline__ void gld_lds16(const void* g, void* l){
  __builtin_amdgcn_global_load_lds(
      (const __attribute__((address_space(1))) unsigned int*)g,
      (__attribute__((address_space(3))) unsigned int*)l, 16, 0, 0);
}

// ---------------- prep: fp32 -> bf16 convert (x) ----------------
__global__ __launch_bounds__(256) void cvt_bf16(const float* __restrict__ src,
                                                unsigned short* __restrict__ dst, int n4){
  int i = blockIdx.x*256 + threadIdx.x;
  if (i < n4){
    float4 v = ((const float4*)src)[i];
    ushort4 o;
    o.x = f2bf(v.x); o.y = f2bf(v.y); o.z = f2bf(v.z); o.w = f2bf(v.w);
    ((ushort4*)dst)[i] = o;
  }
}

// ---------------- prep: all 4 weight matrices -> bf16, one launch ----------------
// dst layout: [Wq | Wk | Wv | Wo], each DIM*DIM
__global__ __launch_bounds__(256) void cvt_w4(
    const float* __restrict__ wq, const float* __restrict__ wk,
    const float* __restrict__ wv, const float* __restrict__ wo,
    unsigned short* __restrict__ dst){
  int i = blockIdx.x*256 + threadIdx.x;       // 4 * DIM*DIM/4 threads
  int which = i >> 18;                        // DIM*DIM/4 = 1<<18
  int j = i & ((1<<18)-1);
  const float* src = which==0 ? wq : which==1 ? wk : which==2 ? wv : wo;
  float4 v = ((const float4*)src)[j];
  ushort4 o;
  o.x = f2bf(v.x); o.y = f2bf(v.y); o.z = f2bf(v.z); o.w = f2bf(v.w);
  ((ushort4*)dst)[i] = o;
}

// ---------------- prep: RoPE cos/sin table (SEQ x 32 fp32) ----------------
__global__ __launch_bounds__(256) void rope_tab(float* __restrict__ ctab,
                                                float* __restrict__ stab){
  int i = blockIdx.x*256 + threadIdx.x;     // exactly SEQ*32 threads
  int t = i >> 5, j = i & 31;
  float freq = (float)t * powf(10000.0f, -(float)j * (1.0f/32.0f));
  ctab[i] = cosf(freq);
  stab[i] = sinf(freq);
}

// ---------------- bt-GEMM: C = A(MxK) * B(NxK)^T, bf16 MFMA ----------------
// MODE 0: QKV projection + fused RoPE (+0.125 scale on q), outb = qkv (3,B,H,T,HD) bf16
// MODE 1: O projection + x residual, outf = h (NTOK x DIM) fp32  (d_out)
template<int MODE>
__global__ __launch_bounds__(256) void gemm_bt(
    const unsigned short* __restrict__ A,
    const unsigned short* __restrict__ Bw,
    const float* __restrict__ ctab, const float* __restrict__ stab,
    const float* __restrict__ xres,
    unsigned short* __restrict__ outb,
    float* __restrict__ outf,
    int M, int N, int K)
{
  __shared__ unsigned short As[128*64];
  __shared__ unsigned short Bs[128*64];
  const int tid = threadIdx.x;
  const int w = tid >> 6, l = tid & 63;
  const int lr = l & 15, lg = l >> 4;
  const int nbm = M >> 7;
  const int bm = blockIdx.x % nbm;
  const int bn = blockIdx.x / nbm;
  const int wr = w >> 1, wc = w & 1;          // 2x2 waves -> 64x64 each
  const int srow = l >> 3;                    // staging: row within 8-row chunk
  const int scol = (l & 7) * 8;               // staging: element offset in row

  const f32x4 fzero = {0.f,0.f,0.f,0.f};
  f32x4 acc[4][4];
#pragma unroll
  for (int mt = 0; mt < 4; ++mt)
#pragma unroll
    for (int nt = 0; nt < 4; ++nt) acc[mt][nt] = fzero;

  const size_t abase = (size_t)(bm*128)*K;
  const size_t bbase = (size_t)(bn*128)*K;

  for (int k0 = 0; k0 < K; k0 += 64) {
    __syncthreads();                           // prev-iter LDS reads done
#pragma unroll
    for (int ci = 0; ci < 4; ++ci) {
      int c = w*4 + ci;                        // wave-uniform chunk id
      int row = c*8 + srow;
      gld_lds16(A  + abase + (size_t)row*K + k0 + scol, (char*)As + c*1024);
      gld_lds16(Bw + bbase + (size_t)row*K + k0 + scol, (char*)Bs + c*1024);
    }
    __syncthreads();                           // staging drained before reads
#pragma unroll
    for (int ks = 0; ks < 2; ++ks) {
      bf16x8 af[4], bfr[4];
#pragma unroll
      for (int mt = 0; mt < 4; ++mt)
        af[mt] = *(const bf16x8*)(As + (wr*64 + mt*16 + lr)*64 + ks*32 + lg*8);
#pragma unroll
      for (int nt = 0; nt < 4; ++nt)
        bfr[nt] = *(const bf16x8*)(Bs + (wc*64 + nt*16 + lr)*64 + ks*32 + lg*8);
#pragma unroll
      for (int mt = 0; mt < 4; ++mt)
#pragma unroll
        for (int nt = 0; nt < 4; ++nt)
          acc[mt][nt] = __builtin_amdgcn_mfma_f32_16x16x32_bf16(af[mt], bfr[nt], acc[mt][nt], 0, 0, 0);
    }
  }

  const int mb = bm*128 + wr*64;
  const int nb = bn*128 + wc*64;               // 64-col block => single head/section
  if (MODE == 0) {
    const int which = nb >> 10;                // 0=q 1=k 2=v
    const int h = (nb & 1023) >> 6;
    const size_t secbase = (size_t)which * ((size_t)BSZ*HEADS*SEQ*HD);
#pragma unroll
    for (int mt = 0; mt < 4; ++mt) {
#pragma unroll
      for (int r = 0; r < 4; ++r) {
        int m = mb + mt*16 + lg*4 + r;         // C/D layout: row=(lane>>4)*4+r
        int b = m >> 11, t = m & (SEQ-1);
        float v[4];
#pragma unroll
        for (int nt = 0; nt < 4; ++nt) v[nt] = acc[mt][nt][r];
        if (which < 2) {                       // RoPE on q,k: pair (hd, hd+32) = (nt, nt+2)
#pragma unroll
          for (int nt = 0; nt < 2; ++nt) {
            int hd = nt*16 + lr;               // < 32
            float c = ctab[t*32 + hd], s = stab[t*32 + hd];
            float v0 = v[nt], v1 = v[nt+2];
            v[nt]   = v0*c - v1*s;
            v[nt+2] = v1*c + v0*s;
          }
          if (which == 0) {                    // fold softmax scale 1/sqrt(64) into q
#pragma unroll
            for (int nt = 0; nt < 4; ++nt) v[nt] *= 0.125f;
          }
        }
        size_t ob = secbase + ((size_t)(b*HEADS + h)*SEQ + t) * HD;
#pragma unroll
        for (int nt = 0; nt < 4; ++nt)
          outb[ob + nt*16 + lr] = f2bf(v[nt]);
      }
    }
  } else {
#pragma unroll
    for (int mt = 0; mt < 4; ++mt) {
#pragma unroll
      for (int r = 0; r < 4; ++r) {
        int m = mb + mt*16 + lg*4 + r;
        size_t rowb = (size_t)m * DIM;
#pragma unroll
        for (int nt = 0; nt < 4; ++nt) {
          int n = nb + nt*16 + lr;
          outf[rowb + n] = acc[mt][nt][r] + xres[rowb + n];
        }
      }
    }
  }
}

// ---------------- V global transpose: [b][h][t][d] -> [b][h][d][t] ----------------
__global__ __launch_bounds__(256) void vtrans(
    const unsigned short* __restrict__ vin,
    unsigned short* __restrict__ vT)
{
  __shared__ unsigned short T[64][65];
  const int tid = threadIdx.x;
  const int bh = blockIdx.x >> 5;
  const int t0 = (blockIdx.x & 31) * 64;
  const unsigned short* src = vin + ((size_t)bh*SEQ + t0) * HD;
  for (int i = tid; i < 512; i += 256) {
    int r = i >> 3, c8 = (i & 7) * 8;
    *(bf16x8*)(&T[r][c8]) = *(const bf16x8*)(src + r*HD + c8);
  }
  __syncthreads();
  for (int i = tid; i < 512; i += 256) {
    int d = i >> 3, tc8 = (i & 7) * 8;
    bf16x8 o;
#pragma unroll
    for (int j = 0; j < 8; ++j) ((unsigned short*)&o)[j] = T[tc8+j][d];
    *(bf16x8*)(vT + ((size_t)bh*HD + d)*SEQ + t0 + tc8) = o;
  }
}

// ---------------- flash attention ----------------
// block = (b,h, 64 q-rows), 4 waves x 16 q-rows.
// K,V^T tiles in XOR-swizzled stride-64 LDS staged via global_load_lds
// (linear dest, pre-swizzled source chunk = (l&7)^(l>>3); read applies same XOR).
// P at stride 72 (conflict-free, per-wave region, no barrier).
// LDS = 8K + 8K + 9.2K = 25.6KB -> 6 blocks/CU.
__global__ __launch_bounds__(256) void attn_fwd(
    const unsigned short* __restrict__ qkv,   // q,k sections [b][h][t][d]
    const unsigned short* __restrict__ vT,    // [b][h][d][t]
    const int* __restrict__ amask,
    unsigned short* __restrict__ aout)
{
  __shared__ unsigned short Kls[64*64];
  __shared__ unsigned short Vls[64*64];
  __shared__ unsigned short Pls[64*72];
  const int tid = threadIdx.x;
  const int w = tid >> 6, l = tid & 63;
  const int lr = l & 15, lg = l >> 4;
  const int bh = blockIdx.x >> 5;        // b*16+h
  const int qb = blockIdx.x & 31;
  const int b = bh >> 4;
  const size_t SEC = (size_t)BSZ*HEADS*SEQ*HD;
  const unsigned short* Qp = qkv + (size_t)bh*SEQ*HD;
  const unsigned short* Kp = Qp + SEC;
  const unsigned short* Vp = vT + (size_t)bh*HD*SEQ;

  // staging: per-lane source swizzle (row&7 = l>>3 since wave row-base % 8 == 0)
  const int srow   = l >> 3;                    // 0..7
  const int schunk = ((l & 7) ^ srow) * 8;      // source element offset in row

  // Q A-frags held in registers (prescaled by 0.125 in gemm0)
  const int qrow = qb*64 + w*16 + lr;
  bf16x8 qf[2];
#pragma unroll
  for (int ks = 0; ks < 2; ++ks)
    qf[ks] = *(const bf16x8*)(Qp + (size_t)qrow*HD + ks*32 + lg*8);

  const f32x4 fzero = {0.f,0.f,0.f,0.f};
  f32x4 o[4];
#pragma unroll
  for (int dt = 0; dt < 4; ++dt) o[dt] = fzero;
  float mrun[4], lrun[4];
#pragma unroll
  for (int r = 0; r < 4; ++r){ mrun[r] = -1e30f; lrun[r] = 0.f; }

  for (int kt = 0; kt < SEQ/64; ++kt) {
    __syncthreads();                      // prev-tile LDS reads done
    // stage K and V^T tiles: 2 passes x (K,V), dest linear base+lane*16
#pragma unroll
    for (int c = 0; c < 2; ++c) {
      const int rb = (c*4 + w)*8;         // wave-uniform row base
      gld_lds16(Kp + (size_t)(kt*64 + rb + srow)*HD + schunk,
                (char*)Kls + (c*4 + w)*1024);
      gld_lds16(Vp + (size_t)(rb + srow)*SEQ + kt*64 + schunk,
                (char*)Vls + (c*4 + w)*1024);
    }
    __syncthreads();                      // staging drained

    // S = Q K^T for this wave's 16 q-rows x 64 keys
    f32x4 s[4];
#pragma unroll
    for (int nt = 0; nt < 4; ++nt) s[nt] = fzero;
#pragma unroll
    for (int ks = 0; ks < 2; ++ks) {
#pragma unroll
      for (int nt = 0; nt < 4; ++nt) {
        bf16x8 kf = *(const bf16x8*)(&Kls[(nt*16+lr)*64 + (((ks*4+lg) ^ (lr&7))*8)]);
        s[nt] = __builtin_amdgcn_mfma_f32_16x16x32_bf16(qf[ks], kf, s[nt], 0, 0, 0);
      }
    }

    // online softmax (fp32); lane holds col(key)=lr of tiles nt, rows(q) lg*4+r
    float addm[4];
#pragma unroll
    for (int nt = 0; nt < 4; ++nt)
      addm[nt] = (1.0f - (float)amask[b*SEQ + kt*64 + nt*16 + lr]) * 1e9f;
    float corr[4];
    float pv[4][4];
#pragma unroll
    for (int r = 0; r < 4; ++r) {
      float mx = -1e30f;
#pragma unroll
      for (int nt = 0; nt < 4; ++nt) {
        float vv = s[nt][r] - addm[nt];
        pv[nt][r] = vv;
        mx = fmaxf(mx, vv);
      }
#pragma unroll
      for (int d = 8; d >= 1; d >>= 1) mx = fmaxf(mx, __shfl_xor(mx, d));
      float mnew = fmaxf(mrun[r], mx);
      corr[r] = __expf(mrun[r] - mnew);
      float rsum = 0.f;
#pragma unroll
      for (int nt = 0; nt < 4; ++nt) {
        float p = __expf(pv[nt][r] - mnew);
        pv[nt][r] = p;
        rsum += p;
      }
#pragma unroll
      for (int d = 8; d >= 1; d >>= 1) rsum += __shfl_xor(rsum, d);
      lrun[r] = lrun[r] * corr[r] + rsum;
      mrun[r] = mnew;
    }
#pragma unroll
    for (int dt = 0; dt < 4; ++dt)
#pragma unroll
      for (int r = 0; r < 4; ++r)
        o[dt][r] *= corr[r];

    // P -> per-wave LDS region (no barrier needed), re-read as A-frags
#pragma unroll
    for (int nt = 0; nt < 4; ++nt)
#pragma unroll
      for (int r = 0; r < 4; ++r)
        Pls[(w*16 + lg*4 + r)*72 + nt*16 + lr] = f2bf(pv[nt][r]);

#pragma unroll
    for (int ks = 0; ks < 2; ++ks) {
      bf16x8 pf = *(const bf16x8*)(&Pls[(w*16+lr)*72 + ks*32 + lg*8]);
#pragma unroll
      for (int dt = 0; dt < 4; ++dt) {
        bf16x8 vf = *(const bf16x8*)(&Vls[(dt*16+lr)*64 + (((ks*4+lg) ^ (lr&7))*8)]);
        o[dt] = __builtin_amdgcn_mfma_f32_16x16x32_bf16(pf, vf, o[dt], 0, 0, 0);
      }
    }
  }

  const int h = bh & (HEADS-1);
#pragma unroll
  for (int r = 0; r < 4; ++r) {
    float inv = 1.0f / lrun[r];
    int t = qb*64 + w*16 + lg*4 + r;
    size_t rowb = (size_t)(b*SEQ + t) * DIM + h*HD;
#pragma unroll
    for (int dt = 0; dt < 4; ++dt)
      aout[rowb + dt*16 + lr] = f2bf(o[dt][r] * inv);
  }
}

// ---------------- LayerNorm: fp32 in-place on d_out ----------------
__global__ __launch_bounds__(256) void layernorm_inplace(
    float* __restrict__ hbuf,
    const float* __restrict__ gamma, const float* __restrict__ beta)
{
  const int row = blockIdx.x;
  const int tid = threadIdx.x;
  const int w = tid >> 6, l = tid & 63;
  __shared__ float red[8];
  float* hr = hbuf + (size_t)row * DIM;
  float4 v = *(const float4*)(hr + tid*4);
  float s = v.x+v.y+v.z+v.w;
#pragma unroll
  for (int d = 32; d >= 1; d >>= 1) s += __shfl_xor(s, d);
  if (l == 0) red[w] = s;
  __syncthreads();
  float mu = (red[0]+red[1]+red[2]+red[3]) * (1.0f/DIM);
  float d0=v.x-mu, d1=v.y-mu, d2=v.z-mu, d3=v.w-mu;
  float q = d0*d0+d1*d1+d2*d2+d3*d3;
#pragma unroll
  for (int d = 32; d >= 1; d >>= 1) q += __shfl_xor(q, d);
  if (l == 0) red[4+w] = q;
  __syncthreads();
  float var = (red[4]+red[5]+red[6]+red[7]) * (1.0f/DIM);
  float rstd = rsqrtf(var + 1e-5f);
  int c = tid*4;
  float4 ou;
  ou.x = d0*rstd*gamma[c+0]+beta[c+0];
  ou.y = d1*rstd*gamma[c+1]+beta[c+1];
  ou.z = d2*rstd*gamma[c+2]+beta[c+2];
  ou.w = d3*rstd*gamma[c+3]+beta[c+3];
  *(float4*)(hr + c) = ou;
}

extern "C" void kernel_launch(void* const* d_in, const int* in_sizes, int n_in,
                              void* d_out, int out_size, void* d_ws, size_t ws_size,
                              hipStream_t stream) {
  const float* x     = (const float*)d_in[0];
  const int*   amask = (const int*)  d_in[1];
  const float* Wq    = (const float*)d_in[2];
  const float* Wk    = (const float*)d_in[3];
  const float* Wv    = (const float*)d_in[4];
  const float* Wo    = (const float*)d_in[5];
  const float* gamma = (const float*)d_in[6];
  const float* beta  = (const float*)d_in[7];

  // workspace layout (~92.8 MB, proven to fit)
  unsigned short* xb   = (unsigned short*)d_ws;                       // NTOK*DIM bf16 (dead after gemm0 -> reused as vT)
  unsigned short* Wqkv = xb + (size_t)NTOK*DIM;                       // 3*DIM*DIM bf16
  unsigned short* Wob  = Wqkv + (size_t)3*DIM*DIM;                    // DIM*DIM bf16 (contiguous after Wqkv)
  unsigned short* qkv  = Wob + (size_t)DIM*DIM;                       // 3*NTOK*DIM bf16
  unsigned short* aout = qkv + (size_t)3*NTOK*DIM;                    // NTOK*DIM bf16
  float* ctab = (float*)(aout + (size_t)NTOK*DIM);                    // SEQ*32 f32
  float* stab = ctab + SEQ*32;

  unsigned short* vT = xb;       // V^T [b][h][d][t], reuses xb after gemm0
  float* hout = (float*)d_out;   // fp32 h, then LN in-place

  // prep
  cvt_bf16<<<(NTOK*DIM/4 + 255)/256, 256, 0, stream>>>(x, xb, NTOK*DIM/4);
  cvt_w4<<<4*DIM*DIM/4/256, 256, 0, stream>>>(Wq, Wk, Wv, Wo, Wqkv);
  rope_tab<<<SEQ*32/256, 256, 0, stream>>>(ctab, stab);

  // QKV projection + RoPE + q-scale  (M=8192, N=3072, K=1024)
  gemm_bt<0><<<(NTOK/128)*(3*DIM/128), 256, 0, stream>>>(
      xb, Wqkv, ctab, stab, nullptr, qkv, nullptr, NTOK, 3*DIM, DIM);

  // V -> V^T (xb region is dead now)
  vtrans<<<BSZ*HEADS*(SEQ/64), 256, 0, stream>>>(qkv + (size_t)2*BSZ*HEADS*SEQ*HD, vT);

  // attention
  attn_fwd<<<BSZ*HEADS*(SEQ/64), 256, 0, stream>>>(qkv, vT, amask, aout);

  // O projection + residual  (M=8192, N=1024, K=1024) -> fp32 h in d_out
  gemm_bt<1><<<(NTOK/128)*(DIM/128), 256, 0, stream>>>(
      aout, Wob, nullptr, nullptr, x, nullptr, hout, NTOK, DIM, DIM);

  // LayerNorm in-place on d_out (fp32)
  layernorm_inplace<<<NTOK, 256, 0, stream>>>(hout, gamma, beta);
}

// Round 7
// 376.116 us; speedup vs baseline: 1.4814x; 1.2126x over previous
//
#include <hip/hip_runtime.h>
#include <hip/hip_bf16.h>
#include <math.h>

#define DIM    1024
#define HEADS  16
#define HD     64
#define BSZ    4
#define SEQ    2048
#define NTOK   (BSZ*SEQ)          // 8192

typedef __attribute__((ext_vector_type(4))) float f32x4;
typedef __attribute__((ext_vector_type(8))) short bf16x8;

__device__ __forceinline__ unsigned short f2bf(float f){
  union { float f; unsigned int i; } v; v.f = f;
  unsigned int u = v.i;
  u += 0x7fffu + ((u >> 16) & 1u);   // RNE
  return (unsigned short)(u >> 16);
}
__device__ __forceinline__ void gld_lds16(const void* g, void* l){
  __builtin_amdgcn_global_load_lds(
      (const __attribute__((address_space(1))) unsigned int*)g,
      (__attribute__((address_space(3))) unsigned int*)l, 16, 0, 0);
}

// ---------------- prep: fp32 -> bf16 convert (x) ----------------
__global__ __launch_bounds__(256) void cvt_bf16(const float* __restrict__ src,
                                                unsigned short* __restrict__ dst, int n4){
  int i = blockIdx.x*256 + threadIdx.x;
  if (i < n4){
    float4 v = ((const float4*)src)[i];
    ushort4 o;
    o.x = f2bf(v.x); o.y = f2bf(v.y); o.z = f2bf(v.z); o.w = f2bf(v.w);
    ((ushort4*)dst)[i] = o;
  }
}

// ---------------- prep: all 4 weight matrices -> bf16, one launch ----------------
// dst layout: [Wq | Wk | Wv | Wo], each DIM*DIM
__global__ __launch_bounds__(256) void cvt_w4(
    const float* __restrict__ wq, const float* __restrict__ wk,
    const float* __restrict__ wv, const float* __restrict__ wo,
    unsigned short* __restrict__ dst){
  int i = blockIdx.x*256 + threadIdx.x;       // 4 * DIM*DIM/4 threads
  int which = i >> 18;                        // DIM*DIM/4 = 1<<18
  int j = i & ((1<<18)-1);
  const float* src = which==0 ? wq : which==1 ? wk : which==2 ? wv : wo;
  float4 v = ((const float4*)src)[j];
  ushort4 o;
  o.x = f2bf(v.x); o.y = f2bf(v.y); o.z = f2bf(v.z); o.w = f2bf(v.w);
  ((ushort4*)dst)[i] = o;
}

// ---------------- prep: RoPE cos/sin table (SEQ x 32 fp32) ----------------
__global__ __launch_bounds__(256) void rope_tab(float* __restrict__ ctab,
                                                float* __restrict__ stab){
  int i = blockIdx.x*256 + threadIdx.x;     // exactly SEQ*32 threads
  int t = i >> 5, j = i & 31;
  float freq = (float)t * powf(10000.0f, -(float)j * (1.0f/32.0f));
  ctab[i] = cosf(freq);
  stab[i] = sinf(freq);
}

// ---------------- prep: additive mask int -> float ----------------
__global__ __launch_bounds__(256) void cvt_mask(const int* __restrict__ am,
                                                float* __restrict__ out, int n){
  int i = blockIdx.x*256 + threadIdx.x;
  if (i < n) out[i] = (1.0f - (float)am[i]) * 1e9f;
}

// ---------------- bt-GEMM: C = A(MxK) * B(NxK)^T, bf16 MFMA ----------------
// MODE 0: QKV projection + fused RoPE (+0.125 scale on q), outb = qkv (3,B,H,T,HD) bf16
// MODE 1: O projection + x residual, outf = h (NTOK x DIM) fp32  (d_out)
template<int MODE>
__global__ __launch_bounds__(256) void gemm_bt(
    const unsigned short* __restrict__ A,
    const unsigned short* __restrict__ Bw,
    const float* __restrict__ ctab, const float* __restrict__ stab,
    const float* __restrict__ xres,
    unsigned short* __restrict__ outb,
    float* __restrict__ outf,
    int M, int N, int K)
{
  __shared__ unsigned short As[128*64];
  __shared__ unsigned short Bs[128*64];
  const int tid = threadIdx.x;
  const int w = tid >> 6, l = tid & 63;
  const int lr = l & 15, lg = l >> 4;
  const int nbm = M >> 7;
  const int bm = blockIdx.x % nbm;
  const int bn = blockIdx.x / nbm;
  const int wr = w >> 1, wc = w & 1;          // 2x2 waves -> 64x64 each
  const int srow = l >> 3;                    // staging: row within 8-row chunk
  const int scol = (l & 7) * 8;               // staging: element offset in row

  const f32x4 fzero = {0.f,0.f,0.f,0.f};
  f32x4 acc[4][4];
#pragma unroll
  for (int mt = 0; mt < 4; ++mt)
#pragma unroll
    for (int nt = 0; nt < 4; ++nt) acc[mt][nt] = fzero;

  const size_t abase = (size_t)(bm*128)*K;
  const size_t bbase = (size_t)(bn*128)*K;

  for (int k0 = 0; k0 < K; k0 += 64) {
    __syncthreads();                           // prev-iter LDS reads done
#pragma unroll
    for (int ci = 0; ci < 4; ++ci) {
      int c = w*4 + ci;                        // wave-uniform chunk id
      int row = c*8 + srow;
      gld_lds16(A  + abase + (size_t)row*K + k0 + scol, (char*)As + c*1024);
      gld_lds16(Bw + bbase + (size_t)row*K + k0 + scol, (char*)Bs + c*1024);
    }
    __syncthreads();                           // staging drained before reads
#pragma unroll
    for (int ks = 0; ks < 2; ++ks) {
      bf16x8 af[4], bfr[4];
#pragma unroll
      for (int mt = 0; mt < 4; ++mt)
        af[mt] = *(const bf16x8*)(As + (wr*64 + mt*16 + lr)*64 + ks*32 + lg*8);
#pragma unroll
      for (int nt = 0; nt < 4; ++nt)
        bfr[nt] = *(const bf16x8*)(Bs + (wc*64 + nt*16 + lr)*64 + ks*32 + lg*8);
#pragma unroll
      for (int mt = 0; mt < 4; ++mt)
#pragma unroll
        for (int nt = 0; nt < 4; ++nt)
          acc[mt][nt] = __builtin_amdgcn_mfma_f32_16x16x32_bf16(af[mt], bfr[nt], acc[mt][nt], 0, 0, 0);
    }
  }

  const int mb = bm*128 + wr*64;
  const int nb = bn*128 + wc*64;               // 64-col block => single head/section
  if (MODE == 0) {
    const int which = nb >> 10;                // 0=q 1=k 2=v
    const int h = (nb & 1023) >> 6;
    const size_t secbase = (size_t)which * ((size_t)BSZ*HEADS*SEQ*HD);
#pragma unroll
    for (int mt = 0; mt < 4; ++mt) {
#pragma unroll
      for (int r = 0; r < 4; ++r) {
        int m = mb + mt*16 + lg*4 + r;         // C/D layout: row=(lane>>4)*4+r
        int b = m >> 11, t = m & (SEQ-1);
        float v[4];
#pragma unroll
        for (int nt = 0; nt < 4; ++nt) v[nt] = acc[mt][nt][r];
        if (which < 2) {                       // RoPE on q,k: pair (hd, hd+32) = (nt, nt+2)
#pragma unroll
          for (int nt = 0; nt < 2; ++nt) {
            int hd = nt*16 + lr;               // < 32
            float c = ctab[t*32 + hd], s = stab[t*32 + hd];
            float v0 = v[nt], v1 = v[nt+2];
            v[nt]   = v0*c - v1*s;
            v[nt+2] = v1*c + v0*s;
          }
          if (which == 0) {                    // fold softmax scale 1/sqrt(64) into q
#pragma unroll
            for (int nt = 0; nt < 4; ++nt) v[nt] *= 0.125f;
          }
        }
        size_t ob = secbase + ((size_t)(b*HEADS + h)*SEQ + t) * HD;
#pragma unroll
        for (int nt = 0; nt < 4; ++nt)
          outb[ob + nt*16 + lr] = f2bf(v[nt]);
      }
    }
  } else {
#pragma unroll
    for (int mt = 0; mt < 4; ++mt) {
#pragma unroll
      for (int r = 0; r < 4; ++r) {
        int m = mb + mt*16 + lg*4 + r;
        size_t rowb = (size_t)m * DIM;
#pragma unroll
        for (int nt = 0; nt < 4; ++nt) {
          int n = nb + nt*16 + lr;
          outf[rowb + n] = acc[mt][nt][r] + xres[rowb + n];
        }
      }
    }
  }
}

// ---------------- V global transpose: [b][h][t][d] -> [b][h][d][t] ----------------
__global__ __launch_bounds__(256) void vtrans(
    const unsigned short* __restrict__ vin,
    unsigned short* __restrict__ vT)
{
  __shared__ unsigned short T[64][65];
  const int tid = threadIdx.x;
  const int bh = blockIdx.x >> 5;
  const int t0 = (blockIdx.x & 31) * 64;
  const unsigned short* src = vin + ((size_t)bh*SEQ + t0) * HD;
  for (int i = tid; i < 512; i += 256) {
    int r = i >> 3, c8 = (i & 7) * 8;
    *(bf16x8*)(&T[r][c8]) = *(const bf16x8*)(src + r*HD + c8);
  }
  __syncthreads();
  for (int i = tid; i < 512; i += 256) {
    int d = i >> 3, tc8 = (i & 7) * 8;
    bf16x8 o;
#pragma unroll
    for (int j = 0; j < 8; ++j) ((unsigned short*)&o)[j] = T[tc8+j][d];
    *(bf16x8*)(vT + ((size_t)bh*HD + d)*SEQ + t0 + tc8) = o;
  }
}

// ---------------- flash attention ----------------
// block = (b,h, 64 q-rows), 4 waves x 16 q-rows.
// K,V^T in XOR-swizzled stride-64 LDS via global_load_lds; P stride-72 per-wave.
// Softmax: deferred-max (rescale only when excess > 8, ~never) + per-lane
// deferred denominator (one cross-lane reduce at the end), truncating bf16 P.
__global__ __launch_bounds__(256) void attn_fwd(
    const unsigned short* __restrict__ qkv,   // q,k sections [b][h][t][d]
    const unsigned short* __restrict__ vT,    // [b][h][d][t]
    const float* __restrict__ maskadd,        // (1-mask)*1e9, fp32 [b][t]
    unsigned short* __restrict__ aout)
{
  __shared__ unsigned short Kls[64*64];
  __shared__ unsigned short Vls[64*64];
  __shared__ unsigned short Pls[64*72];
  const int tid = threadIdx.x;
  const int w = tid >> 6, l = tid & 63;
  const int lr = l & 15, lg = l >> 4;
  const int bh = blockIdx.x >> 5;        // b*16+h
  const int qb = blockIdx.x & 31;
  const int b = bh >> 4;
  const size_t SEC = (size_t)BSZ*HEADS*SEQ*HD;
  const unsigned short* Qp = qkv + (size_t)bh*SEQ*HD;
  const unsigned short* Kp = Qp + SEC;
  const unsigned short* Vp = vT + (size_t)bh*HD*SEQ;

  // staging: per-lane source swizzle (row&7 = l>>3 since wave row-base % 8 == 0)
  const int srow   = l >> 3;                    // 0..7
  const int schunk = ((l & 7) ^ srow) * 8;      // source element offset in row

  // Q A-frags held in registers (prescaled by 0.125 in gemm0)
  const int qrow = qb*64 + w*16 + lr;
  bf16x8 qf[2];
#pragma unroll
  for (int ks = 0; ks < 2; ++ks)
    qf[ks] = *(const bf16x8*)(Qp + (size_t)qrow*HD + ks*32 + lg*8);

  const f32x4 fzero = {0.f,0.f,0.f,0.f};
  f32x4 o[4];
#pragma unroll
  for (int dt = 0; dt < 4; ++dt) o[dt] = fzero;
  float mrun[4], lrun[4];
#pragma unroll
  for (int r = 0; r < 4; ++r){ mrun[r] = -1e30f; lrun[r] = 0.f; }

  for (int kt = 0; kt < SEQ/64; ++kt) {
    __syncthreads();                      // prev-tile LDS reads done
#pragma unroll
    for (int c = 0; c < 2; ++c) {
      const int rb = (c*4 + w)*8;         // wave-uniform row base
      gld_lds16(Kp + (size_t)(kt*64 + rb + srow)*HD + schunk,
                (char*)Kls + (c*4 + w)*1024);
      gld_lds16(Vp + (size_t)(rb + srow)*SEQ + kt*64 + schunk,
                (char*)Vls + (c*4 + w)*1024);
    }
    __syncthreads();                      // staging drained

    // S = Q K^T for this wave's 16 q-rows x 64 keys
    f32x4 s[4];
#pragma unroll
    for (int nt = 0; nt < 4; ++nt) s[nt] = fzero;
#pragma unroll
    for (int ks = 0; ks < 2; ++ks) {
#pragma unroll
      for (int nt = 0; nt < 4; ++nt) {
        bf16x8 kf = *(const bf16x8*)(&Kls[(nt*16+lr)*64 + (((ks*4+lg) ^ (lr&7))*8)]);
        s[nt] = __builtin_amdgcn_mfma_f32_16x16x32_bf16(qf[ks], kf, s[nt], 0, 0, 0);
      }
    }

    // masked scores; lane holds col(key)=lr of tiles nt, rows(q) lg*4+r
    float pv[4][4];
#pragma unroll
    for (int nt = 0; nt < 4; ++nt) {
      float am = maskadd[b*SEQ + kt*64 + nt*16 + lr];
#pragma unroll
      for (int r = 0; r < 4; ++r)
        pv[nt][r] = s[nt][r] - am;
    }

    // deferred-max check: rescale only if some row exceeds mrun+8 (wave-uniform)
    float excess = 0.f;
#pragma unroll
    for (int r = 0; r < 4; ++r) {
      float mx = fmaxf(fmaxf(pv[0][r], pv[1][r]), fmaxf(pv[2][r], pv[3][r]));
      excess = fmaxf(excess, mx - mrun[r]);
    }
    if (!__all(excess <= 8.0f)) {
#pragma unroll
      for (int r = 0; r < 4; ++r) {
        float rm = fmaxf(fmaxf(pv[0][r], pv[1][r]), fmaxf(pv[2][r], pv[3][r]));
#pragma unroll
        for (int d = 8; d >= 1; d >>= 1) rm = fmaxf(rm, __shfl_xor(rm, d));
        float mnew = fmaxf(mrun[r], rm);
        float corr = __expf(mrun[r] - mnew);
        lrun[r] *= corr;
        mrun[r] = mnew;
#pragma unroll
        for (int dt = 0; dt < 4; ++dt) o[dt][r] *= corr;
      }
    }

    // P = exp(S - m), truncated bf16 (denominator uses SAME truncated values)
#pragma unroll
    for (int r = 0; r < 4; ++r) {
      float sum = 0.f;
#pragma unroll
      for (int nt = 0; nt < 4; ++nt) {
        float p = __expf(pv[nt][r] - mrun[r]);
        union { float f; unsigned int u; } cv; cv.f = p;
        cv.u &= 0xffff0000u;
        sum += cv.f;
        Pls[(w*16 + lg*4 + r)*72 + nt*16 + lr] = (unsigned short)(cv.u >> 16);
      }
      lrun[r] += sum;
    }

#pragma unroll
    for (int ks = 0; ks < 2; ++ks) {
      bf16x8 pf = *(const bf16x8*)(&Pls[(w*16+lr)*72 + ks*32 + lg*8]);
#pragma unroll
      for (int dt = 0; dt < 4; ++dt) {
        bf16x8 vf = *(const bf16x8*)(&Vls[(dt*16+lr)*64 + (((ks*4+lg) ^ (lr&7))*8)]);
        o[dt] = __builtin_amdgcn_mfma_f32_16x16x32_bf16(pf, vf, o[dt], 0, 0, 0);
      }
    }
  }

  const int h = bh & (HEADS-1);
#pragma unroll
  for (int r = 0; r < 4; ++r) {
    float lsum = lrun[r];
#pragma unroll
    for (int d = 8; d >= 1; d >>= 1) lsum += __shfl_xor(lsum, d);
    float inv = 1.0f / lsum;
    int t = qb*64 + w*16 + lg*4 + r;
    size_t rowb = (size_t)(b*SEQ + t) * DIM + h*HD;
#pragma unroll
    for (int dt = 0; dt < 4; ++dt)
      aout[rowb + dt*16 + lr] = f2bf(o[dt][r] * inv);
  }
}

// ---------------- LayerNorm: fp32 in-place on d_out ----------------
__global__ __launch_bounds__(256) void layernorm_inplace(
    float* __restrict__ hbuf,
    const float* __restrict__ gamma, const float* __restrict__ beta)
{
  const int row = blockIdx.x;
  const int tid = threadIdx.x;
  const int w = tid >> 6, l = tid & 63;
  __shared__ float red[8];
  float* hr = hbuf + (size_t)row * DIM;
  float4 v = *(const float4*)(hr + tid*4);
  float s = v.x+v.y+v.z+v.w;
#pragma unroll
  for (int d = 32; d >= 1; d >>= 1) s += __shfl_xor(s, d);
  if (l == 0) red[w] = s;
  __syncthreads();
  float mu = (red[0]+red[1]+red[2]+red[3]) * (1.0f/DIM);
  float d0=v.x-mu, d1=v.y-mu, d2=v.z-mu, d3=v.w-mu;
  float q = d0*d0+d1*d1+d2*d2+d3*d3;
#pragma unroll
  for (int d = 32; d >= 1; d >>= 1) q += __shfl_xor(q, d);
  if (l == 0) red[4+w] = q;
  __syncthreads();
  float var = (red[4]+red[5]+red[6]+red[7]) * (1.0f/DIM);
  float rstd = rsqrtf(var + 1e-5f);
  int c = tid*4;
  float4 ou;
  ou.x = d0*rstd*gamma[c+0]+beta[c+0];
  ou.y = d1*rstd*gamma[c+1]+beta[c+1];
  ou.z = d2*rstd*gamma[c+2]+beta[c+2];
  ou.w = d3*rstd*gamma[c+3]+beta[c+3];
  *(float4*)(hr + c) = ou;
}

extern "C" void kernel_launch(void* const* d_in, const int* in_sizes, int n_in,
                              void* d_out, int out_size, void* d_ws, size_t ws_size,
                              hipStream_t stream) {
  const float* x     = (const float*)d_in[0];
  const int*   amask = (const int*)  d_in[1];
  const float* Wq    = (const float*)d_in[2];
  const float* Wk    = (const float*)d_in[3];
  const float* Wv    = (const float*)d_in[4];
  const float* Wo    = (const float*)d_in[5];
  const float* gamma = (const float*)d_in[6];
  const float* beta  = (const float*)d_in[7];

  // workspace layout (~92.9 MB, proven to fit)
  unsigned short* xb   = (unsigned short*)d_ws;                       // NTOK*DIM bf16 (dead after gemm0 -> reused as vT)
  unsigned short* Wqkv = xb + (size_t)NTOK*DIM;                       // 3*DIM*DIM bf16
  unsigned short* Wob  = Wqkv + (size_t)3*DIM*DIM;                    // DIM*DIM bf16 (contiguous after Wqkv)
  unsigned short* qkv  = Wob + (size_t)DIM*DIM;                       // 3*NTOK*DIM bf16
  unsigned short* aout = qkv + (size_t)3*NTOK*DIM;                    // NTOK*DIM bf16
  float* ctab = (float*)(aout + (size_t)NTOK*DIM);                    // SEQ*32 f32
  float* stab = ctab + SEQ*32;                                        // SEQ*32 f32
  float* madd = stab + SEQ*32;                                        // NTOK f32

  unsigned short* vT = xb;       // V^T [b][h][d][t], reuses xb after gemm0
  float* hout = (float*)d_out;   // fp32 h, then LN in-place

  // prep
  cvt_bf16<<<(NTOK*DIM/4 + 255)/256, 256, 0, stream>>>(x, xb, NTOK*DIM/4);
  cvt_w4<<<4*DIM*DIM/4/256, 256, 0, stream>>>(Wq, Wk, Wv, Wo, Wqkv);
  rope_tab<<<SEQ*32/256, 256, 0, stream>>>(ctab, stab);
  cvt_mask<<<(NTOK + 255)/256, 256, 0, stream>>>(amask, madd, NTOK);

  // QKV projection + RoPE + q-scale  (M=8192, N=3072, K=1024)
  gemm_bt<0><<<(NTOK/128)*(3*DIM/128), 256, 0, stream>>>(
      xb, Wqkv, ctab, stab, nullptr, qkv, nullptr, NTOK, 3*DIM, DIM);

  // V -> V^T (xb region is dead now)
  vtrans<<<BSZ*HEADS*(SEQ/64), 256, 0, stream>>>(qkv + (size_t)2*BSZ*HEADS*SEQ*HD, vT);

  // attention
  attn_fwd<<<BSZ*HEADS*(SEQ/64), 256, 0, stream>>>(qkv, vT, madd, aout);

  // O projection + residual  (M=8192, N=1024, K=1024) -> fp32 h in d_out
  gemm_bt<1><<<(NTOK/128)*(DIM/128), 256, 0, stream>>>(
      aout, Wob, nullptr, nullptr, x, nullptr, hout, NTOK, DIM, DIM);

  // LayerNorm in-place on d_out (fp32)
  layernorm_inplace<<<NTOK, 256, 0, stream>>>(hout, gamma, beta);
}